// Round 1
// 78.481 us; speedup vs baseline: 1.2287x; 1.2287x over previous
//
#include <hip/hip_runtime.h>

// EKV nonlinear conv2d, MI355X.
// out[b,co,h,w] = alpha * sum_{cin,i,j} sp((v-th)*inv)^2 - sp((v-th-0.1)*inv)^2
// log2-domain: e1 = 2^(v*s) * 2^(-th*s), e2 = e1*KF,
//   term = ln2^2 * (log2(1+e1)^2 - log2(1+e2)^2)
//
// v2 changes vs 96.4us baseline:
//  - Sparsity skip: v~N(0,1), th~N(4.5,0.5) => e1 = 2^((v-th)*S) is almost
//    always < 2^-11. If (window vmax) < thmin - 11/S, every term of that
//    (wave,cin) is < 2^-22; skipping adds <= alpha*576*2^-22 ~ 7.8e-8 per
//    output. Block-level: compacted active-cin list (skips stage+barrier too).
//    Wave-level: one LDS broadcast + compare per active cin.
//  - fma form: q2 = q*KF precomputed; a = fma(ev,q,1) -> 7 insts/elem vs 9.
//  - Double-buffered staging (EsA/EsB distinct arrays => compiler overlaps
//    next-plane global load/exp2/ds_write with current-plane compute);
//    1 barrier per active cin instead of 2 per cin.

constexpr int CIN  = 64;
constexpr int COUT = 128;
constexpr int HW   = 32;
constexpr int PIX  = HW * HW;       // 1024
constexpr int ESTR = 44;            // padded-tile row stride (16B-aligned reads)
constexpr int EN   = 34 * ESTR;     // 1496 floats per buffer

__global__ __launch_bounds__(256, 2)
void ekv_kernel(const float* __restrict__ V, const float* __restrict__ Th,
                float* __restrict__ Out)
{
    constexpr float S     = 19.235933878519512f;     // (1/0.075) * log2(e)
    constexpr float KF    = 0.26359713811572677f;    // exp(-0.1/0.075)
    constexpr float OSC   = 2.7025482032899376e-4f;  // alpha * ln2^2
    constexpr float DELTA = 0.5718460f;              // 11/S (rounded down = conservative)

    const int t  = threadIdx.x;          // 0..255
    const int b  = blockIdx.x >> 7;      // /COUT
    const int co = blockIdx.x & (COUT - 1);

    __shared__ float EsA[EN];            // double-buffered exp2(v*S) tiles
    __shared__ float EsB[EN];            // (halo = exp2(0) = 1)
    __shared__ float rowtmp[CIN * HW];   // per-(cin,row) max of V for this b
    __shared__ float Qs[CIN * 9];        // exp2(-theta*S)
    __shared__ float thminD[CIN];        // min_k theta[co][cin][k] - DELTA
    __shared__ float wgvmax[CIN * 4];    // per-(cin, wave-group) window max of V
    __shared__ int   listS[CIN];         // active cin list
    __shared__ int   nactS;

    const float* vbase = V  + (size_t)b  * CIN * PIX;
    const float* thp   = Th + (size_t)co * (CIN * 9);

    // ---------------- prologue ----------------
    for (int i = t; i < EN; i += 256) { EsA[i] = 1.0f; EsB[i] = 1.0f; }

    // per-row max of raw v (init 0.0f also covers the zero-pad halo pixels)
    for (int r = t; r < CIN * HW; r += 256) {            // 8 iters
        const float4* rp = reinterpret_cast<const float4*>(vbase + r * HW);
        float m = 0.0f;
        #pragma unroll
        for (int k = 0; k < 8; ++k) {
            const float4 x = rp[k];
            m = fmaxf(m, fmaxf(fmaxf(x.x, x.y), fmaxf(x.z, x.w)));
        }
        rowtmp[r] = m;
    }

    for (int i = t; i < CIN * 9; i += 256)
        Qs[i] = __builtin_amdgcn_exp2f(-thp[i] * S);

    if (t < CIN) {
        float m = 1e30f;
        #pragma unroll
        for (int k = 0; k < 9; ++k) m = fminf(m, thp[t * 9 + k]);
        thminD[t] = m - DELTA;
    }
    __syncthreads();

    {   // per-(cin, wave-group) max over real rows 8w-1 .. 8w+8 (clamped)
        const int cin = t >> 2, w = t & 3;
        float m = 0.0f;                  // keeps halo-row (v=0) in the bound
        #pragma unroll
        for (int rr = 0; rr < 10; ++rr) {
            int r = 8 * w - 1 + rr;
            r = r < 0 ? 0 : (r > 31 ? 31 : r);
            m = fmaxf(m, rowtmp[cin * HW + r]);
        }
        wgvmax[t] = m;
    }
    __syncthreads();

    if (t == 0) {                        // compact list of block-active cin
        int n = 0;
        for (int c = 0; c < CIN; ++c) {
            const float m = fmaxf(fmaxf(wgvmax[c * 4], wgvmax[c * 4 + 1]),
                                  fmaxf(wgvmax[c * 4 + 2], wgvmax[c * 4 + 3]));
            if (m >= thminD[c]) listS[n++] = c;
        }
        nactS = n;
    }
    __syncthreads();
    const int nact = nactS;

    const int ho   = t >> 3;             // output row   0..31
    const int wb   = (t & 7) * 4;        // output col base
    const int wave = t >> 6;

    float acc0 = 0.f, acc1 = 0.f, acc2 = 0.f, acc3 = 0.f;

    auto stage = [&](float* Es, int cin) {
        const float4 v4 = reinterpret_cast<const float4*>(vbase + cin * PIX)[t];
        const int r = t >> 3, c = (t & 7) * 4;
        float* dst = &Es[(1 + r) * ESTR + 1 + c];
        dst[0] = __builtin_amdgcn_exp2f(v4.x * S);
        dst[1] = __builtin_amdgcn_exp2f(v4.y * S);
        dst[2] = __builtin_amdgcn_exp2f(v4.z * S);
        dst[3] = __builtin_amdgcn_exp2f(v4.w * S);
    };

    auto compute = [&](const float* Es, int cin) {
        // wave-uniform skip: all 64 lanes read the same wgvmax/thminD entry
        if (wgvmax[cin * 4 + wave] < thminD[cin]) return;
        float q1[9], q2[9];
        #pragma unroll
        for (int k = 0; k < 9; ++k) {
            q1[k] = Qs[cin * 9 + k];
            q2[k] = q1[k] * KF;
        }
        #pragma unroll
        for (int i = 0; i < 3; ++i) {
            const float* rowp = &Es[(ho + i) * ESTR + wb];   // 16B aligned
            const float4 m4 = *reinterpret_cast<const float4*>(rowp);
            const float2 n2 = *reinterpret_cast<const float2*>(rowp + 4);
            const float vals[6] = {m4.x, m4.y, m4.z, m4.w, n2.x, n2.y};
            #pragma unroll
            for (int j = 0; j < 3; ++j) {
                const float qa = q1[i * 3 + j];
                const float qb = q2[i * 3 + j];
                #pragma unroll
                for (int k = 0; k < 4; ++k) {
                    const float x1 = __builtin_fmaf(vals[k + j], qa, 1.0f);
                    const float x2 = __builtin_fmaf(vals[k + j], qb, 1.0f);
                    const float l1 = __builtin_amdgcn_logf(x1);   // log2
                    const float l2 = __builtin_amdgcn_logf(x2);
                    const float term = (l1 + l2) * (l1 - l2);     // l1^2-l2^2
                    if (k == 0) acc0 += term;
                    else if (k == 1) acc1 += term;
                    else if (k == 2) acc2 += term;
                    else acc3 += term;
                }
            }
        }
    };

    // ---------------- main loop over active cin, double-buffered ----------------
    if (nact > 0) {
        stage(EsA, listS[0]);
        __syncthreads();
        for (int j = 0; j < nact; ++j) {
            if (!(j & 1)) {
                if (j + 1 < nact) stage(EsB, listS[j + 1]);
                compute(EsA, listS[j]);
            } else {
                if (j + 1 < nact) stage(EsA, listS[j + 1]);
                compute(EsB, listS[j]);
            }
            __syncthreads();
        }
    }

    float4 o;
    o.x = acc0 * OSC; o.y = acc1 * OSC; o.z = acc2 * OSC; o.w = acc3 * OSC;
    // pixel index of (ho, wb+k) = 4*t + k  ->  one coalesced float4 store
    reinterpret_cast<float4*>(Out + (size_t)blockIdx.x * PIX)[t] = o;
}

extern "C" void kernel_launch(void* const* d_in, const int* in_sizes, int n_in,
                              void* d_out, int out_size, void* d_ws, size_t ws_size,
                              hipStream_t stream) {
    (void)in_sizes; (void)n_in; (void)d_ws; (void)ws_size; (void)out_size;
    const float* V  = (const float*)d_in[0];   // (4,64,32,32)
    const float* Th = (const float*)d_in[1];   // (128,64,3,3)
    float* Out = (float*)d_out;                // (4,128,32,32)
    ekv_kernel<<<dim3(4 * COUT), dim3(256), 0, stream>>>(V, Th, Out);
}

// Round 2
// 42.569 us; speedup vs baseline: 2.2653x; 1.8436x over previous
//
#include <hip/hip_runtime.h>

// EKV nonlinear conv2d, MI355X.
// out[b,co,h,w] = alpha * sum_{cin,i,j} sp((v-th)*inv)^2 - sp((v-th-0.1)*inv)^2
// log2-domain: e1 = 2^(v*s) * 2^(-th*s), e2 = e1*KF,
//   term = ln2^2 * (log2(1+e1)^2 - log2(1+e2)^2)
//
// v3 changes vs 78.5us v2 (which was barrier/latency-bound: VALUBusy 23%):
//  - ZERO main-loop barriers: each wave stages its 10-row window into its own
//    private LDS buffer (ds ordering is wave-internal). Waves run fully
//    decoupled with their own __ballot-derived active-cin mask (walked via
//    ctz), so a wave never waits on siblings' staging or skips.
//  - Software pipeline within the wave: next plane's global loads issued into
//    registers before computing current plane from LDS (L2 latency hidden).
//  - Pre-kernel computes the per-(b,cin,window) vmax table into d_ws once
//    (4 KB), removing the 256KB-per-block prologue scan + serial compaction.

constexpr int CIN  = 64;
constexpr int COUT = 128;
constexpr int HW   = 32;
constexpr int PIX  = HW * HW;       // 1024
constexpr int LROW = 40;            // wave-buffer row stride (160B, keeps 16B align)

constexpr float S     = 19.235933878519512f;     // (1/0.075) * log2(e)
constexpr float KF    = 0.26359713811572677f;    // exp(-0.1/0.075)
constexpr float OSC   = 2.7025482032899376e-4f;  // alpha * ln2^2
constexpr float DELTA = 0.5718460f;              // 11/S: skip => per-term < 2^-22

// ---- pre-kernel: wg[(b*CIN+cin)*4 + w] = max V over rows 8w-1..8w+8 (and 0 for halo)
__global__ __launch_bounds__(256)
void ekv_rowmax(const float* __restrict__ V, float* __restrict__ wg)
{
    const int t = threadIdx.x;
    const int plane = blockIdx.x;               // b*CIN + cin
    __shared__ float rmax[32];
    const float4 v4 = reinterpret_cast<const float4*>(V + (size_t)plane * PIX)[t];
    float m = fmaxf(fmaxf(v4.x, v4.y), fmaxf(v4.z, v4.w));
    m = fmaxf(m, __shfl_xor(m, 1));             // reduce 8 lanes of one row
    m = fmaxf(m, __shfl_xor(m, 2));
    m = fmaxf(m, __shfl_xor(m, 4));
    if ((t & 7) == 0) rmax[t >> 3] = m;
    __syncthreads();
    if (t < 4) {
        float wm = 0.0f;                        // halo pixels are v=0 -> e=1
        #pragma unroll
        for (int rr = 0; rr < 10; ++rr) {
            const int r = 8 * t - 1 + rr;
            if (r >= 0 && r < 32) wm = fmaxf(wm, rmax[r]);
        }
        wg[plane * 4 + t] = wm;
    }
}

// ---- main kernel
__global__ __launch_bounds__(256, 2)
void ekv_main(const float* __restrict__ V, const float* __restrict__ Th,
              const float* __restrict__ wg, float* __restrict__ Out)
{
    const int t    = threadIdx.x;
    const int b    = blockIdx.x >> 7;
    const int co   = blockIdx.x & (COUT - 1);
    const int w    = t >> 6;                    // wave 0..3 -> output rows 8w..8w+7
    const int lane = t & 63;

    __shared__ float Ew[4][10 * LROW];          // per-wave private window buffers
    __shared__ float Qs[CIN * 9];               // exp2(-theta*S), block-shared

    const float* vbase = V  + (size_t)b  * CIN * PIX;
    const float* thp   = Th + (size_t)co * (CIN * 9);

    for (int i = t; i < CIN * 9; i += 256)
        Qs[i] = __builtin_amdgcn_exp2f(-thp[i] * S);

    // lane l tests cin=l: active iff window vmax >= min_k(theta)-DELTA
    float thmin = 1e30f;
    #pragma unroll
    for (int k = 0; k < 9; ++k) thmin = fminf(thmin, thp[lane * 9 + k]);
    const float wgv = wg[(size_t)(b * CIN + lane) * 4 + w];
    unsigned long long mask = __ballot(wgv >= thmin - DELTA);

    // one-time halo init of this wave's buffer (never overwritten after)
    float* EB = Ew[w];
    if (lane < 10) { EB[lane * LROW] = 1.0f; EB[lane * LROW + 33] = 1.0f; }
    if (w == 0 && lane < 34) EB[lane] = 1.0f;               // global row -1
    if (w == 3 && lane < 34) EB[9 * LROW + lane] = 1.0f;    // global row 32

    __syncthreads();    // Qs ready; the ONLY block barrier

    const int lr = lane >> 3;                   // 0..7
    const int lc = (lane & 7) * 4;              // 0..28
    // primary load -> buffer row 1+lr (global row 8w+lr, always in range)
    // secondary: lanes 0..7 -> buffer row 0 (global 8w-1), 8..15 -> row 9 (8w+8)
    const bool sec  = (lane < 8) ? (w != 0) : ((lane < 16) ? (w != 3) : false);
    const int  srow = (lane < 8) ? 0 : 9;
    const int  sgr  = 8 * w - 1 + srow;

    float acc0 = 0.f, acc1 = 0.f, acc2 = 0.f, acc3 = 0.f;

    if (mask) {
        int cin = (int)__builtin_ctzll(mask); mask &= mask - 1;
        const float* src = vbase + cin * PIX;
        float4 pa = *reinterpret_cast<const float4*>(src + (8 * w + lr) * HW + lc);
        float4 pb = make_float4(0.f, 0.f, 0.f, 0.f);
        if (sec) pb = *reinterpret_cast<const float4*>(src + sgr * HW + lc);

        for (;;) {
            int nxt = -1;
            if (mask) { nxt = (int)__builtin_ctzll(mask); mask &= mask - 1; }

            // stage current plane into the wave buffer (waits vmcnt on pa/pb)
            {
                float* d = &EB[(1 + lr) * LROW + 1 + lc];
                d[0] = __builtin_amdgcn_exp2f(pa.x * S);
                d[1] = __builtin_amdgcn_exp2f(pa.y * S);
                d[2] = __builtin_amdgcn_exp2f(pa.z * S);
                d[3] = __builtin_amdgcn_exp2f(pa.w * S);
                if (sec) {
                    float* d2 = &EB[srow * LROW + 1 + lc];
                    d2[0] = __builtin_amdgcn_exp2f(pb.x * S);
                    d2[1] = __builtin_amdgcn_exp2f(pb.y * S);
                    d2[2] = __builtin_amdgcn_exp2f(pb.z * S);
                    d2[3] = __builtin_amdgcn_exp2f(pb.w * S);
                }
            }

            // issue next plane's loads now; latency hides under compute below
            float4 na = pa, nb = pb;
            if (nxt >= 0) {
                const float* s2 = vbase + nxt * PIX;
                na = *reinterpret_cast<const float4*>(s2 + (8 * w + lr) * HW + lc);
                if (sec) nb = *reinterpret_cast<const float4*>(s2 + sgr * HW + lc);
            }

            // compute current plane from the wave buffer
            {
                float q1[9], q2[9];
                #pragma unroll
                for (int k = 0; k < 9; ++k) {
                    q1[k] = Qs[cin * 9 + k];    // broadcast reads
                    q2[k] = q1[k] * KF;
                }
                #pragma unroll
                for (int i = 0; i < 3; ++i) {
                    const float* rowp = &EB[(lr + i) * LROW + lc];   // 16B aligned
                    const float4 m4 = *reinterpret_cast<const float4*>(rowp);
                    const float2 n2 = *reinterpret_cast<const float2*>(rowp + 4);
                    const float vals[6] = {m4.x, m4.y, m4.z, m4.w, n2.x, n2.y};
                    #pragma unroll
                    for (int j = 0; j < 3; ++j) {
                        const float qa = q1[i * 3 + j];
                        const float qb = q2[i * 3 + j];
                        #pragma unroll
                        for (int k = 0; k < 4; ++k) {
                            const float x1 = __builtin_fmaf(vals[k + j], qa, 1.0f);
                            const float x2 = __builtin_fmaf(vals[k + j], qb, 1.0f);
                            const float l1 = __builtin_amdgcn_logf(x1);   // log2
                            const float l2 = __builtin_amdgcn_logf(x2);
                            const float su = l1 + l2, di = l1 - l2;       // l1^2-l2^2
                            if      (k == 0) acc0 = __builtin_fmaf(su, di, acc0);
                            else if (k == 1) acc1 = __builtin_fmaf(su, di, acc1);
                            else if (k == 2) acc2 = __builtin_fmaf(su, di, acc2);
                            else             acc3 = __builtin_fmaf(su, di, acc3);
                        }
                    }
                }
            }

            if (nxt < 0) break;
            pa = na; pb = nb; cin = nxt;
        }
    }

    float4 o;
    o.x = acc0 * OSC; o.y = acc1 * OSC; o.z = acc2 * OSC; o.w = acc3 * OSC;
    // pixel (t>>3, lc..lc+3) = flat 4t -> one coalesced float4 store
    reinterpret_cast<float4*>(Out + (size_t)blockIdx.x * PIX)[t] = o;
}

extern "C" void kernel_launch(void* const* d_in, const int* in_sizes, int n_in,
                              void* d_out, int out_size, void* d_ws, size_t ws_size,
                              hipStream_t stream) {
    (void)in_sizes; (void)n_in; (void)ws_size; (void)out_size;
    const float* V  = (const float*)d_in[0];   // (4,64,32,32)
    const float* Th = (const float*)d_in[1];   // (128,64,3,3)
    float* Out = (float*)d_out;                // (4,128,32,32)
    float* wg  = (float*)d_ws;                 // 4*64*4 floats = 4 KB
    ekv_rowmax<<<dim3(4 * CIN), dim3(256), 0, stream>>>(V, wg);
    ekv_main<<<dim3(4 * COUT), dim3(256), 0, stream>>>(V, Th, wg, Out);
}